// Round 8
// baseline (839.529 us; speedup 1.0000x reference)
//
#include <hip/hip_runtime.h>
#include <hip/hip_bf16.h>
#include <math.h>

// ---------------- workspace layout (bytes) ----------------
#define OFF_P0 0
#define OFF_P1 16777216
#define OFF_P2 33554432
#define OFF_DS 37748736
#define OFF_IT 38273024
#define OFF_ST 39059456
#define OFF_AC 39063552

// ---------------- conv 3x3 SAME + bias + relu (v7) ----------------
// v6 structure (16x16 px tile, 1 px x 8 oc/thread, max grid density,
// precomputed staging maps, stride-40 LDS rows) + WEIGHTS IN LDS:
// wl[WCH][8][12] staged every WCH/CB K-steps inside the existing barrier
// window; inner loop reads them as uniform-address b128 broadcasts.
// This replaces per-cc s_load chains that thrashed the scalar cache
// (8 blocks/CU x 18 KB weight sets).
template<int CB, int WCH>
__global__ __launch_bounds__(256) void conv3x3_v7(
    const float* __restrict__ in, const float* __restrict__ w,
    const float* __restrict__ b, float* __restrict__ out,
    int N, int Cin, int Cout, int H, int W)
{
    const int TW = W >> 4, TH = H >> 4, OCG = Cout >> 3;
    int bid = blockIdx.x;
    int txt = bid % TW; bid /= TW;
    int tyt = bid % TH; bid /= TH;
    int ocg = bid % OCG; bid /= OCG;
    int n = bid;
    int x0 = txt * 16, y0 = tyt * 16;
    int tid = threadIdx.x;
    int tx = tid & 15, ty = tid >> 4;

    __shared__ float lin[CB * 720];       // CB x 18 x 40
    __shared__ float wl[WCH * 96];        // WCH x 8 oc x 12 (9 used, 16B-aligned)

    constexpr int NSLOT = CB * 324;
    constexpr int NT = (NSLOT + 255) / 256;

    // ---- precompute staging maps (K-invariant) ----
    int goff[NT], loff[NT];
    unsigned vmask = 0;
    const int HW = H * W;
#pragma unroll
    for (int t = 0; t < NT; ++t) {
        int i = tid + t * 256;
        int cc = i / 324;
        int rem = i - cc * 324;
        int r = rem / 18;
        int c = rem - r * 18;
        int y = y0 - 1 + r, x = x0 - 1 + c;
        goff[t] = cc * HW + y * W + x;
        loff[t] = cc * 720 + r * 40 + c;
        if (i < NSLOT && (unsigned)y < (unsigned)H && (unsigned)x < (unsigned)W)
            vmask |= (1u << t);
        else
            goff[t] = 0;
        if (i >= NSLOT) loff[t] = -1;
    }

    float acc[8];
#pragma unroll
    for (int oc = 0; oc < 8; ++oc) acc[oc] = 0.f;

    const float* in_n = in + (size_t)n * Cin * HW;
    const float* w_g  = w + (size_t)(ocg * 8) * Cin * 9;

    for (int c0 = 0; c0 < Cin; c0 += CB) {
        const float* ip = in_n + (size_t)c0 * HW;
        __syncthreads();
        // stage weights for the next WCH input channels (amortized barrier)
        if ((c0 % WCH) == 0) {
            for (int i = tid; i < WCH * 72; i += 256) {
                int cc = i / 72;
                int rem = i - cc * 72;
                int oc = rem / 9;
                int j = rem - oc * 9;
                wl[cc * 96 + oc * 12 + j] = w_g[((size_t)oc * Cin + c0 + cc) * 9 + j];
            }
        }
        // stage input tile (CB x 18 x 18, zero-padded halo)
#pragma unroll
        for (int t = 0; t < NT; ++t) {
            if (loff[t] >= 0) {
                float v = (vmask & (1u << t)) ? ip[goff[t]] : 0.f;
                lin[loff[t]] = v;
            }
        }
        __syncthreads();

        int wbase = (c0 % WCH) * 96;
#pragma unroll
        for (int cc = 0; cc < CB; ++cc) {
            const float* base = &lin[cc * 720 + ty * 40 + tx];
            float i00 = base[0];
            float i01 = base[1];
            float i02 = base[2];
            float i10 = base[40];
            float i11 = base[41];
            float i12 = base[42];
            float i20 = base[80];
            float i21 = base[81];
            float i22 = base[82];
            const float* wrow = &wl[wbase + cc * 96];
#pragma unroll
            for (int oc = 0; oc < 8; ++oc) {
                const float* wq = wrow + oc * 12;        // uniform -> LDS broadcast
                float4 wa = *(const float4*)wq;
                float4 wb = *(const float4*)(wq + 4);
                float  w8 = wq[8];
                float a = acc[oc];
                a = fmaf(wa.x, i00, a);
                a = fmaf(wa.y, i01, a);
                a = fmaf(wa.z, i02, a);
                a = fmaf(wa.w, i10, a);
                a = fmaf(wb.x, i11, a);
                a = fmaf(wb.y, i12, a);
                a = fmaf(wb.z, i20, a);
                a = fmaf(wb.w, i21, a);
                a = fmaf(w8,   i22, a);
                acc[oc] = a;
            }
        }
    }

#pragma unroll
    for (int oc = 0; oc < 8; ++oc) {
        float v = acc[oc] + b[ocg * 8 + oc];
        v = fmaxf(v, 0.f);
        out[((size_t)(n * Cout + ocg * 8 + oc) * H + (y0 + ty)) * W + (x0 + tx)] = v;
    }
}

// ---------------- 2x2 pools ----------------
__global__ __launch_bounds__(256) void maxpool2_k(const float* __restrict__ in,
                                                  float* __restrict__ out, int total)
{
    int tid = blockIdx.x * 256 + threadIdx.x;
    if (tid >= total) return;
    int wo = tid & 63, ho = (tid >> 6) & 63, ch = tid >> 12;
    const float* p = in + (size_t)ch * 16384 + (size_t)(ho * 2) * 128 + wo * 2;
    out[tid] = fmaxf(fmaxf(p[0], p[1]), fmaxf(p[128], p[129]));
}

__global__ __launch_bounds__(256) void avgpool2_k(const float* __restrict__ in,
                                                  float* __restrict__ out, int total)
{
    int tid = blockIdx.x * 256 + threadIdx.x;
    if (tid >= total) return;
    int wo = tid & 63, ho = (tid >> 6) & 63, ch = tid >> 12;
    const float* p = in + (size_t)ch * 16384 + (size_t)(ho * 2) * 128 + wo * 2;
    out[tid] = 0.25f * ((p[0] + p[1]) + (p[128] + p[129]));
}

// ---------------- batchnorm stats ----------------
__global__ __launch_bounds__(256) void bn_stats_k(const float* __restrict__ x,
                                                  float* __restrict__ stats,
                                                  int C, int HW, int N)
{
    int c = blockIdx.x, tid = threadIdx.x;
    int M = N * HW;
    double s = 0.0, s2 = 0.0;
    for (int i = tid; i < M; i += 256) {
        int n = i / HW, r = i - n * HW;
        float v = x[((size_t)(n * C + c)) * HW + r];
        s += v;
        s2 += (double)v * (double)v;
    }
    __shared__ double ls[256], ls2[256];
    ls[tid] = s; ls2[tid] = s2;
    __syncthreads();
    for (int st = 128; st > 0; st >>= 1) {
        if (tid < st) { ls[tid] += ls[tid + st]; ls2[tid] += ls2[tid + st]; }
        __syncthreads();
    }
    if (tid == 0) {
        double mean = ls[0] / M;
        double var = ls2[0] / M - mean * mean;
        stats[c] = (float)mean;
        stats[C + c] = (float)(1.0 / sqrt(var + 1e-5));
    }
}

// ---------------- normalize + transpose fich: (4,128,64,64)->(4,64,64,128) ---
__global__ __launch_bounds__(256) void norm_transpose_f_k(
    const float* __restrict__ x, const float* __restrict__ stats,
    float* __restrict__ xt)
{
    int bid = blockIdx.x;           // n(4) x h(64) x ct(4) x wt(2)
    int wt = bid & 1; bid >>= 1;
    int ct = bid & 3; bid >>= 2;
    int h = bid & 63; bid >>= 6;
    int n = bid;
    int tx = threadIdx.x & 31, ty = threadIdx.x >> 5;
    __shared__ float lds[32][33];
    int c0 = ct * 32, w0 = wt * 32;
#pragma unroll
    for (int i = 0; i < 4; ++i) {
        int c = c0 + ty + i * 8;
        float v = x[(((size_t)n * 128 + c) * 64 + h) * 64 + (w0 + tx)];
        lds[ty + i * 8][tx] = (v - stats[c]) * stats[128 + c];
    }
    __syncthreads();
#pragma unroll
    for (int i = 0; i < 4; ++i) {
        int wcol = w0 + ty + i * 8;
        xt[(((size_t)(n * 64) + h) * 64 + wcol) * 128 + c0 + tx] = lds[tx][ty + i * 8];
    }
}

// ---------------- normalize + transpose images ----------------
__global__ __launch_bounds__(256) void norm_transpose_i_k(
    const float* __restrict__ x, const float* __restrict__ stats,
    float* __restrict__ it)
{
    int tid = blockIdx.x * 256 + threadIdx.x;   // 65536
    int n = tid >> 14;
    int hw = tid & 16383;
#pragma unroll
    for (int c = 0; c < 3; ++c) {
        float v = x[(((size_t)n * 3 + c) << 14) + hw];
        it[(size_t)tid * 3 + c] = (v - stats[c]) * stats[3 + c];
    }
}

__global__ void zero_k(float* acc)
{
    if (threadIdx.x < 128) acc[threadIdx.x] = 0.f;
}

// ---------------- modularity on VGG features (v2) ----------------
__global__ __launch_bounds__(64) void modularity64_v2(
    const float* __restrict__ xt,   // (4,64,64,128)
    const float* __restrict__ seg,  // (4,8,64,64)
    float* __restrict__ acc)        // [0..31] num, [32..63] den
{
    __shared__ float fl[12][12][20];
    __shared__ float sl[8][12][14];

    int t = threadIdx.x;
    int tx = t & 7, ty = t >> 3;
    int bid = blockIdx.x;              // n(4) x by(8) x bx(8)
    int bx = bid & 7; bid >>= 3;
    int by = bid & 7; bid >>= 3;
    int n = bid;
    int x0 = bx * 8, y0 = by * 8;

    for (int i = t; i < 8 * 144; i += 64) {
        int k = i / 144;
        int rem = i - k * 144;
        int r = rem / 12, c = rem - r * 12;
        int y = y0 - 2 + r, x = x0 - 2 + c;
        float v = 0.f;
        if ((unsigned)y < 64u && (unsigned)x < 64u)
            v = seg[((size_t)(n * 8 + k) * 64 + y) * 64 + x];
        sl[k][r][c] = v;
    }

    float d2p[25];
#pragma unroll
    for (int di = 0; di < 5; ++di)
#pragma unroll
        for (int dj = 0; dj < 5; ++dj) {
            int y2 = y0 + ty + di - 2, x2 = x0 + tx + dj - 2;
            d2p[di * 5 + dj] = ((unsigned)y2 < 64u && (unsigned)x2 < 64u) ? 0.f : 1e30f;
        }

    for (int ch0 = 0; ch0 < 128; ch0 += 16) {
        __syncthreads();
        for (int i = t; i < 576; i += 64) {
            int pix = i >> 2, q = i & 3;
            int r = pix / 12, c = pix - r * 12;
            int y = y0 - 2 + r, x = x0 - 2 + c;
            float4 v = make_float4(0.f, 0.f, 0.f, 0.f);
            if ((unsigned)y < 64u && (unsigned)x < 64u)
                v = *(const float4*)&xt[((size_t)((n * 64 + y) * 64 + x)) * 128 + ch0 + q * 4];
            *(float4*)&fl[r][c][q * 4] = v;
        }
        __syncthreads();

        float4 c0 = *(const float4*)&fl[ty + 2][tx + 2][0];
        float4 c1 = *(const float4*)&fl[ty + 2][tx + 2][4];
        float4 c2 = *(const float4*)&fl[ty + 2][tx + 2][8];
        float4 c3 = *(const float4*)&fl[ty + 2][tx + 2][12];
#pragma unroll
        for (int di = 0; di < 5; ++di)
#pragma unroll
            for (int dj = 0; dj < 5; ++dj) {
                const float* np = &fl[ty + di][tx + dj][0];
                float4 v0 = *(const float4*)(np + 0);
                float4 v1 = *(const float4*)(np + 4);
                float4 v2 = *(const float4*)(np + 8);
                float4 v3 = *(const float4*)(np + 12);
                float d = d2p[di * 5 + dj];
                float e;
                e = c0.x - v0.x; d = fmaf(e, e, d);
                e = c0.y - v0.y; d = fmaf(e, e, d);
                e = c0.z - v0.z; d = fmaf(e, e, d);
                e = c0.w - v0.w; d = fmaf(e, e, d);
                e = c1.x - v1.x; d = fmaf(e, e, d);
                e = c1.y - v1.y; d = fmaf(e, e, d);
                e = c1.z - v1.z; d = fmaf(e, e, d);
                e = c1.w - v1.w; d = fmaf(e, e, d);
                e = c2.x - v2.x; d = fmaf(e, e, d);
                e = c2.y - v2.y; d = fmaf(e, e, d);
                e = c2.z - v2.z; d = fmaf(e, e, d);
                e = c2.w - v2.w; d = fmaf(e, e, d);
                e = c3.x - v3.x; d = fmaf(e, e, d);
                e = c3.y - v3.y; d = fmaf(e, e, d);
                e = c3.z - v3.z; d = fmaf(e, e, d);
                e = c3.w - v3.w; d = fmaf(e, e, d);
                d2p[di * 5 + dj] = d;
            }
    }

    const float minus_inv2s2 = -1.0f / (2.0f * 0.02f * 0.02f); // -1250
    float wgt[25];
    float w1 = 0.f;
#pragma unroll
    for (int j = 0; j < 25; ++j) {
        wgt[j] = expf(d2p[j] * minus_inv2s2);
        w1 += wgt[j];
    }

#pragma unroll
    for (int k = 0; k < 8; ++k) {
        float s = 0.f;
#pragma unroll
        for (int di = 0; di < 5; ++di)
#pragma unroll
            for (int dj = 0; dj < 5; ++dj)
                s = fmaf(wgt[di * 5 + dj], sl[k][ty + di][tx + dj], s);
        float sc = sl[k][ty + 2][tx + 2];
        float numk = s * sc;
        float denk = w1 * sc;
#pragma unroll
        for (int sft = 32; sft > 0; sft >>= 1) {
            numk += __shfl_xor(numk, sft, 64);
            denk += __shfl_xor(denk, sft, 64);
        }
        if (t == 0) {
            atomicAdd(&acc[n * 8 + k], numk);
            atomicAdd(&acc[32 + n * 8 + k], denk);
        }
    }
}

// ---------------- modularity on images ----------------
__global__ __launch_bounds__(256) void modularity128_k(
    const float* __restrict__ it,   // (4,128,128,3)
    const float* __restrict__ seg,  // (4,8,128,128)
    float* __restrict__ acc)
{
    const float inv2s2 = 1.0f / (2.0f * 0.2f * 0.2f);
    int tid = blockIdx.x * 256 + threadIdx.x;
    int lane = threadIdx.x & 63;
    int w = tid & 127;
    int h = (tid >> 7) & 127;
    int n = tid >> 14;

    const float* cp = it + (size_t)tid * 3;
    float c0 = cp[0], c1 = cp[1], c2 = cp[2];
    float segc[8], num[8];
#pragma unroll
    for (int k = 0; k < 8; ++k) {
        segc[k] = seg[((size_t)(n * 8 + k) * 128 + h) * 128 + w];
        num[k] = 0.f;
    }
    float w1 = 0.f;

    for (int di = -2; di <= 2; ++di) {
        int h2 = h + di;
        if (h2 < 0 || h2 >= 128) continue;
        for (int dj = -2; dj <= 2; ++dj) {
            int w2 = w + dj;
            if (w2 < 0 || w2 >= 128) continue;
            const float* vp = it + ((size_t)((n * 128 + h2) * 128 + w2)) * 3;
            float d0 = c0 - vp[0], d1 = c1 - vp[1], d2v = c2 - vp[2];
            float d2 = fmaf(d2v, d2v, fmaf(d1, d1, d0 * d0));
            float wgt = expf(-d2 * inv2s2);
            w1 += wgt;
            const float* sp = seg + ((size_t)(n * 8) * 128 + h2) * 128 + w2;
#pragma unroll
            for (int k = 0; k < 8; ++k)
                num[k] = fmaf(sp[(size_t)k * 16384], wgt, num[k]);
        }
    }

    float val;
#pragma unroll
    for (int k = 0; k < 8; ++k) {
        val = num[k] * segc[k];
#pragma unroll
        for (int s = 32; s > 0; s >>= 1) val += __shfl_xor(val, s, 64);
        if (lane == 0) atomicAdd(&acc[64 + n * 8 + k], val);
        val = w1 * segc[k];
#pragma unroll
        for (int s = 32; s > 0; s >>= 1) val += __shfl_xor(val, s, 64);
        if (lane == 0) atomicAdd(&acc[96 + n * 8 + k], val);
    }
}

__global__ void finalize_k(const float* __restrict__ acc, float* __restrict__ out)
{
    int l = threadIdx.x;
    float v = 0.f;
    if (l < 32) v = acc[l] / acc[32 + l] + acc[64 + l] / acc[96 + l];
#pragma unroll
    for (int s = 32; s > 0; s >>= 1) v += __shfl_xor(v, s, 64);
    if (l == 0) out[0] = v * (1.0f / 64.0f);
}

extern "C" void kernel_launch(void* const* d_in, const int* in_sizes, int n_in,
                              void* d_out, int out_size, void* d_ws, size_t ws_size,
                              hipStream_t stream)
{
    const float* images = (const float*)d_in[0];
    const float* seg    = (const float*)d_in[1];
    const float* w1 = (const float*)d_in[2]; const float* b1 = (const float*)d_in[3];
    const float* w2 = (const float*)d_in[4]; const float* b2 = (const float*)d_in[5];
    const float* w3 = (const float*)d_in[6]; const float* b3 = (const float*)d_in[7];
    const float* w4 = (const float*)d_in[8]; const float* b4 = (const float*)d_in[9];
    float* out = (float*)d_out;
    char* ws = (char*)d_ws;
    float* P0 = (float*)(ws + OFF_P0);
    float* P1 = (float*)(ws + OFF_P1);
    float* P2 = (float*)(ws + OFF_P2);
    float* DS = (float*)(ws + OFF_DS);
    float* IT = (float*)(ws + OFF_IT);
    float* ST = (float*)(ws + OFF_ST);
    float* AC = (float*)(ws + OFF_AC);

    // VGG stem — grid = N * (Cout/8) * (H/16) * (W/16)
    conv3x3_v7<3, 3><<<2048, 256, 0, stream>>>(images, w1, b1, P0, 4, 3, 64, 128, 128);
    conv3x3_v7<4, 16><<<2048, 256, 0, stream>>>(P0, w2, b2, P1, 4, 64, 64, 128, 128);
    maxpool2_k<<<4096, 256, 0, stream>>>(P1, P2, 1048576);
    conv3x3_v7<4, 16><<<1024, 256, 0, stream>>>(P2, w3, b3, P0, 4, 64, 128, 64, 64);
    conv3x3_v7<4, 16><<<1024, 256, 0, stream>>>(P0, w4, b4, P1, 4, 128, 128, 64, 64);

    // batchnorm stats
    bn_stats_k<<<128, 256, 0, stream>>>(P1, ST, 128, 4096, 4);
    bn_stats_k<<<3, 256, 0, stream>>>(images, ST + 256, 3, 16384, 4);

    // normalize + transpose
    norm_transpose_f_k<<<2048, 256, 0, stream>>>(P1, ST, P0);
    norm_transpose_i_k<<<256, 256, 0, stream>>>(images, ST + 256, IT);

    // downsample segmentation 128 -> 64
    avgpool2_k<<<512, 256, 0, stream>>>(seg, DS, 131072);

    // modularity terms
    zero_k<<<1, 128, 0, stream>>>(AC);
    modularity64_v2<<<256, 64, 0, stream>>>(P0, DS, AC);
    modularity128_k<<<256, 256, 0, stream>>>(IT, seg, AC);

    finalize_k<<<1, 64, 0, stream>>>(AC, out);
}

// Round 9
// 457.025 us; speedup vs baseline: 1.8369x; 1.8369x over previous
//
#include <hip/hip_runtime.h>
#include <hip/hip_bf16.h>
#include <math.h>

typedef __attribute__((ext_vector_type(8))) short short8;
typedef __attribute__((ext_vector_type(4))) float floatx4;
typedef unsigned short ushortT;

__device__ inline short f2bf(float v) {
    __hip_bfloat16 h = __float2bfloat16(v);
    union { __hip_bfloat16 h; short s; } u; u.h = h; return u.s;
}

// ---------------- workspace layout (bytes), all disjoint ----------------
#define OFF_C2    0          // conv2 out bf16 NHWC (4,128,128,64)      8,388,608
#define OFF_PAD4  8388608    // conv3 out bf16 NHWC padded (4,66,66,128) 4,460,544
#define OFF_FICH  12849152   // conv4 out fp32 NHWC (4,64,64,128)       8,388,608
#define OFF_PAD2  21237760   // conv1 out bf16 NHWC padded (4,130,130,64) 8,652,800
#define OFF_PAD3  29890560   // pooled bf16 NHWC padded (4,66,66,64)    2,230,272
#define OFF_WP2   32120832   // prepacked w2 frags 73,728 B
#define OFF_WP3   32194560   // 147,456 B
#define OFF_WP4   32342016   // 294,912 B
#define OFF_DS    32636928   // down_seg fp32 (4,8,64,64) 524,288
#define OFF_IT    33161216   // img normalized (4,128,128,3) fp32 786,432
#define OFF_ST    33947648   // [0..127] rstdF; [256..261] img mean/rstd
#define OFF_AC    33949696   // [0..127] modularity acc; [128..255] sumF; [256..383] sum2F

#define PAD2_BYTES 8652800
#define PAD3_BYTES 2230272
#define PAD4_BYTES 4460544

// ---------------- conv1: fp32 direct (Cin=3), writes bf16 NHWC padded --------
__global__ __launch_bounds__(256) void conv1_bf16(
    const float* __restrict__ in, const float* __restrict__ w,
    const float* __restrict__ b, short* __restrict__ outp)
{
    int bid = blockIdx.x;                 // 4n x 8ocg x 8ty x 8tx
    int txt = bid & 7; bid >>= 3;
    int tyt = bid & 7; bid >>= 3;
    int ocg = bid & 7; bid >>= 3;
    int n = bid;
    int x0 = txt * 16, y0 = tyt * 16;
    int tid = threadIdx.x;
    int tx = tid & 15, ty = tid >> 4;

    __shared__ float lds[3 * 720];
    for (int i = tid; i < 972; i += 256) {
        int cc = i / 324; int rem = i - cc * 324;
        int r = rem / 18, c = rem - r * 18;
        int y = y0 - 1 + r, x = x0 - 1 + c;
        float v = 0.f;
        if ((unsigned)y < 128u && (unsigned)x < 128u)
            v = in[((size_t)(n * 3 + cc) * 128 + y) * 128 + x];
        lds[cc * 720 + r * 40 + c] = v;
    }
    __syncthreads();

    float acc[8];
#pragma unroll
    for (int oc = 0; oc < 8; ++oc) acc[oc] = 0.f;
    const float* w_g = w + (size_t)(ocg * 8) * 27;
#pragma unroll
    for (int cc = 0; cc < 3; ++cc) {
        const float* base = &lds[cc * 720 + ty * 40 + tx];
        float i00 = base[0],  i01 = base[1],  i02 = base[2];
        float i10 = base[40], i11 = base[41], i12 = base[42];
        float i20 = base[80], i21 = base[81], i22 = base[82];
        const float* wp = w_g + cc * 9;
#pragma unroll
        for (int oc = 0; oc < 8; ++oc) {
            const float* wq = wp + oc * 27;
            float a = acc[oc];
            a = fmaf(wq[0], i00, a); a = fmaf(wq[1], i01, a); a = fmaf(wq[2], i02, a);
            a = fmaf(wq[3], i10, a); a = fmaf(wq[4], i11, a); a = fmaf(wq[5], i12, a);
            a = fmaf(wq[6], i20, a); a = fmaf(wq[7], i21, a); a = fmaf(wq[8], i22, a);
            acc[oc] = a;
        }
    }
    int oy = y0 + ty, ox = x0 + tx;
    short* o = outp + ((size_t)(n * 130 + oy + 1) * 130 + ox + 1) * 64 + ocg * 8;
#pragma unroll
    for (int oc = 0; oc < 8; ++oc) {
        float v = fmaxf(acc[oc] + b[ocg * 8 + oc], 0.f);
        o[oc] = f2bf(v);
    }
}

// ---------------- weight prepack into MFMA B-fragment order ------------------
// wp element e: j=e&7, L=(e>>3)&63, nt=(e>>9)%NTALL, kt=((e>>9)/NTALL)%KT,
// t=((e>>9)/NTALL)/KT; value = w[oc=nt*16+(L&15)][ci=kt*32+(L>>4)*8+j][tap t]
__global__ void prepack_w(const float* __restrict__ w, short* __restrict__ wp,
                          int CIN, int NTALL, int total)
{
    int e = blockIdx.x * 256 + threadIdx.x;
    if (e >= total) return;
    int j = e & 7; int L = (e >> 3) & 63; int rest = e >> 9;
    int nt = rest % NTALL; int rest2 = rest / NTALL;
    int KT = CIN / 32;
    int kt = rest2 % KT; int t = rest2 / KT;
    int oc = nt * 16 + (L & 15);
    int ci = kt * 32 + (L >> 4) * 8 + j;
    wp[e] = f2bf(w[((size_t)oc * CIN + ci) * 9 + t]);
}

// ---------------- MFMA implicit-GEMM 3x3 conv --------------------------------
// Input: padded NHWC bf16 (Hp=H+2, Wp=W+2, CIN), zero halo -> no bounds checks.
// Block: 32 px (strip in one row) x 64 oc; wave = 16px-half x 32oc-half.
// K-loop: (CIN/32) chunks x 9 taps; per tap: 1 A-frag (16B/lane, direct global)
// + 2 B-frags (prepacked) + 2 MFMA. No LDS, no barriers.
// OUTMODE: 0 = bf16 NHWC unpadded, 1 = bf16 NHWC padded(+1), 2 = fp32 NHWC.
template<int CIN, int COUT, int H, int W, int OUTMODE>
__global__ __launch_bounds__(256) void conv_mfma(
    const short* __restrict__ inp, const short* __restrict__ wp,
    const float* __restrict__ bias, void* __restrict__ outv)
{
    constexpr int KT = CIN / 32;
    constexpr int NTALL = COUT / 16;
    constexpr int NTB = COUT / 64;
    constexpr int TPR = W / 32;
    constexpr int Hp = H + 2, Wp = W + 2;

    int bm = blockIdx.x / NTB;
    int bn = blockIdx.x - bm * NTB;
    int n = bm / (H * TPR);
    int rem = bm - n * (H * TPR);
    int y = rem / TPR;
    int x0 = (rem - y * TPR) * 32;

    int tid = threadIdx.x;
    int wv = tid >> 6, lane = tid & 63;
    int lm = lane & 15, q = lane >> 4;
    int px0 = x0 + 16 * (wv & 1);
    int ntb = bn * 4 + (wv >> 1) * 2;

    floatx4 acc0 = {0.f, 0.f, 0.f, 0.f};
    floatx4 acc1 = {0.f, 0.f, 0.f, 0.f};

    const short* a_m = inp + lm * CIN + q * 8;
    const short* wbase = wp + ((size_t)ntb * 64 + lane) * 8;

    for (int kt = 0; kt < KT; ++kt) {
        int kofs = kt * 32;
#pragma unroll
        for (int r = 0; r < 3; ++r) {
            const short* arow = a_m + (size_t)((n * Hp + y + r) * Wp + px0) * CIN + kofs;
#pragma unroll
            for (int s = 0; s < 3; ++s) {
                short8 av = *(const short8*)(arow + s * CIN);
                const short* bp = wbase + (size_t)(((r * 3 + s) * KT + kt) * NTALL) * 512;
                short8 b0 = *(const short8*)bp;
                short8 b1 = *(const short8*)(bp + 512);
                acc0 = __builtin_amdgcn_mfma_f32_16x16x32_bf16(av, b0, acc0, 0, 0, 0);
                acc1 = __builtin_amdgcn_mfma_f32_16x16x32_bf16(av, b1, acc1, 0, 0, 0);
            }
        }
    }

    // epilogue: D layout col(oc)=lane&15, row(px)=q*4+i
#pragma unroll
    for (int half = 0; half < 2; ++half) {
        floatx4 a = half ? acc1 : acc0;
        int oc = (ntb + half) * 16 + lm;
        float bs = bias[oc];
#pragma unroll
        for (int i = 0; i < 4; ++i) {
            int px = px0 + q * 4 + i;
            float v = fmaxf(a[i] + bs, 0.f);
            if constexpr (OUTMODE == 0) {
                ((short*)outv)[((size_t)(n * H + y) * W + px) * COUT + oc] = f2bf(v);
            } else if constexpr (OUTMODE == 1) {
                ((short*)outv)[((size_t)(n * Hp + y + 1) * Wp + px + 1) * COUT + oc] = f2bf(v);
            } else {
                ((float*)outv)[((size_t)(n * H + y) * W + px) * COUT + oc] = v;
            }
        }
    }
}

// ---------------- 2x2 maxpool, bf16 NHWC -> padded NHWC ----------------------
// relu outputs >= 0 -> raw ushort compare == float compare for bf16.
__global__ __launch_bounds__(256) void maxpool_nhwc(const ushortT* __restrict__ in,
                                                    ushortT* __restrict__ outp)
{
    int gid = blockIdx.x * 256 + threadIdx.x;   // 131072 = 4*64*64*8
    int c8 = gid & 7; int rest = gid >> 3;
    int xo = rest & 63, yo = (rest >> 6) & 63, n = rest >> 12;
    const ushortT* p = in + ((size_t)(n * 128 + yo * 2) * 128 + xo * 2) * 64 + c8 * 8;
    const ushortT* p01 = p + 64;
    const ushortT* p10 = p + 128 * 64;
    const ushortT* p11 = p10 + 64;
    ushortT* o = outp + ((size_t)(n * 66 + yo + 1) * 66 + xo + 1) * 64 + c8 * 8;
#pragma unroll
    for (int j = 0; j < 8; ++j) {
        ushortT a = p[j] > p01[j] ? p[j] : p01[j];
        ushortT b = p10[j] > p11[j] ? p10[j] : p11[j];
        o[j] = a > b ? a : b;
    }
}

// ---------------- BN over NHWC fich: partial sums via atomics ----------------
__global__ __launch_bounds__(256) void bnsum_nhwc(const float* __restrict__ x,
                                                  float* __restrict__ sums)
{
    int c = threadIdx.x & 127;
    int h = threadIdx.x >> 7;
    int p0 = blockIdx.x * 64 + h * 32;
    float s = 0.f, s2 = 0.f;
    for (int p = p0; p < p0 + 32; ++p) {
        float v = x[(size_t)p * 128 + c];
        s += v; s2 = fmaf(v, v, s2);
    }
    atomicAdd(&sums[c], s);
    atomicAdd(&sums[128 + c], s2);
}

__global__ void stats_fin(const float* __restrict__ sums, float* __restrict__ st)
{
    int c = threadIdx.x;   // 128
    float mean = sums[c] * (1.f / 16384.f);
    float var = sums[128 + c] * (1.f / 16384.f) - mean * mean;
    st[c] = 1.f / sqrtf(var + 1e-5f);
}

// scale-only normalization (mean cancels in d2 differences)
__global__ __launch_bounds__(256) void scale_fich(float* __restrict__ x,
                                                  const float* __restrict__ st)
{
    int i = blockIdx.x * 256 + threadIdx.x;    // 524288 float4s
    float4 v = ((float4*)x)[i];
    int c0 = (i * 4) & 127;
    v.x *= st[c0]; v.y *= st[c0 + 1]; v.z *= st[c0 + 2]; v.w *= st[c0 + 3];
    ((float4*)x)[i] = v;
}

// ---------------- image-branch kernels (unchanged, fp32) ---------------------
__global__ __launch_bounds__(256) void avgpool2_k(const float* __restrict__ in,
                                                  float* __restrict__ out, int total)
{
    int tid = blockIdx.x * 256 + threadIdx.x;
    if (tid >= total) return;
    int wo = tid & 63, ho = (tid >> 6) & 63, ch = tid >> 12;
    const float* p = in + (size_t)ch * 16384 + (size_t)(ho * 2) * 128 + wo * 2;
    out[tid] = 0.25f * ((p[0] + p[1]) + (p[128] + p[129]));
}

__global__ __launch_bounds__(256) void bn_stats_k(const float* __restrict__ x,
                                                  float* __restrict__ stats,
                                                  int C, int HW, int N)
{
    int c = blockIdx.x, tid = threadIdx.x;
    int M = N * HW;
    double s = 0.0, s2 = 0.0;
    for (int i = tid; i < M; i += 256) {
        int n = i / HW, r = i - n * HW;
        float v = x[((size_t)(n * C + c)) * HW + r];
        s += v;
        s2 += (double)v * (double)v;
    }
    __shared__ double ls[256], ls2[256];
    ls[tid] = s; ls2[tid] = s2;
    __syncthreads();
    for (int st = 128; st > 0; st >>= 1) {
        if (tid < st) { ls[tid] += ls[tid + st]; ls2[tid] += ls2[tid + st]; }
        __syncthreads();
    }
    if (tid == 0) {
        double mean = ls[0] / M;
        double var = ls2[0] / M - mean * mean;
        stats[c] = (float)mean;
        stats[C + c] = (float)(1.0 / sqrt(var + 1e-5));
    }
}

__global__ __launch_bounds__(256) void norm_transpose_i_k(
    const float* __restrict__ x, const float* __restrict__ stats,
    float* __restrict__ it)
{
    int tid = blockIdx.x * 256 + threadIdx.x;   // 65536
    int n = tid >> 14;
    int hw = tid & 16383;
#pragma unroll
    for (int c = 0; c < 3; ++c) {
        float v = x[(((size_t)n * 3 + c) << 14) + hw];
        it[(size_t)tid * 3 + c] = (v - stats[c]) * stats[3 + c];
    }
}

__global__ void zero_k(float* acc)
{
    acc[threadIdx.x] = 0.f;    // 512 threads
}

// ---------------- modularity on VGG features (unchanged) ---------------------
__global__ __launch_bounds__(64) void modularity64_v2(
    const float* __restrict__ xt,   // (4,64,64,128) scaled
    const float* __restrict__ seg,  // (4,8,64,64)
    float* __restrict__ acc)
{
    __shared__ float fl[12][12][20];
    __shared__ float sl[8][12][14];

    int t = threadIdx.x;
    int tx = t & 7, ty = t >> 3;
    int bid = blockIdx.x;
    int bx = bid & 7; bid >>= 3;
    int by = bid & 7; bid >>= 3;
    int n = bid;
    int x0 = bx * 8, y0 = by * 8;

    for (int i = t; i < 8 * 144; i += 64) {
        int k = i / 144;
        int rem = i - k * 144;
        int r = rem / 12, c = rem - r * 12;
        int y = y0 - 2 + r, x = x0 - 2 + c;
        float v = 0.f;
        if ((unsigned)y < 64u && (unsigned)x < 64u)
            v = seg[((size_t)(n * 8 + k) * 64 + y) * 64 + x];
        sl[k][r][c] = v;
    }

    float d2p[25];
#pragma unroll
    for (int di = 0; di < 5; ++di)
#pragma unroll
        for (int dj = 0; dj < 5; ++dj) {
            int y2 = y0 + ty + di - 2, x2 = x0 + tx + dj - 2;
            d2p[di * 5 + dj] = ((unsigned)y2 < 64u && (unsigned)x2 < 64u) ? 0.f : 1e30f;
        }

    for (int ch0 = 0; ch0 < 128; ch0 += 16) {
        __syncthreads();
        for (int i = t; i < 576; i += 64) {
            int pix = i >> 2, qq = i & 3;
            int r = pix / 12, c = pix - r * 12;
            int y = y0 - 2 + r, x = x0 - 2 + c;
            float4 v = make_float4(0.f, 0.f, 0.f, 0.f);
            if ((unsigned)y < 64u && (unsigned)x < 64u)
                v = *(const float4*)&xt[((size_t)((n * 64 + y) * 64 + x)) * 128 + ch0 + qq * 4];
            *(float4*)&fl[r][c][qq * 4] = v;
        }
        __syncthreads();

        float4 c0 = *(const float4*)&fl[ty + 2][tx + 2][0];
        float4 c1 = *(const float4*)&fl[ty + 2][tx + 2][4];
        float4 c2 = *(const float4*)&fl[ty + 2][tx + 2][8];
        float4 c3 = *(const float4*)&fl[ty + 2][tx + 2][12];
#pragma unroll
        for (int di = 0; di < 5; ++di)
#pragma unroll
            for (int dj = 0; dj < 5; ++dj) {
                const float* np = &fl[ty + di][tx + dj][0];
                float4 v0 = *(const float4*)(np + 0);
                float4 v1 = *(const float4*)(np + 4);
                float4 v2 = *(const float4*)(np + 8);
                float4 v3 = *(const float4*)(np + 12);
                float d = d2p[di * 5 + dj];
                float e;
                e = c0.x - v0.x; d = fmaf(e, e, d);
                e = c0.y - v0.y; d = fmaf(e, e, d);
                e = c0.z - v0.z; d = fmaf(e, e, d);
                e = c0.w - v0.w; d = fmaf(e, e, d);
                e = c1.x - v1.x; d = fmaf(e, e, d);
                e = c1.y - v1.y; d = fmaf(e, e, d);
                e = c1.z - v1.z; d = fmaf(e, e, d);
                e = c1.w - v1.w; d = fmaf(e, e, d);
                e = c2.x - v2.x; d = fmaf(e, e, d);
                e = c2.y - v2.y; d = fmaf(e, e, d);
                e = c2.z - v2.z; d = fmaf(e, e, d);
                e = c2.w - v2.w; d = fmaf(e, e, d);
                e = c3.x - v3.x; d = fmaf(e, e, d);
                e = c3.y - v3.y; d = fmaf(e, e, d);
                e = c3.z - v3.z; d = fmaf(e, e, d);
                e = c3.w - v3.w; d = fmaf(e, e, d);
                d2p[di * 5 + dj] = d;
            }
    }

    const float minus_inv2s2 = -1.0f / (2.0f * 0.02f * 0.02f);
    float wgt[25];
    float w1 = 0.f;
#pragma unroll
    for (int j = 0; j < 25; ++j) {
        wgt[j] = expf(d2p[j] * minus_inv2s2);
        w1 += wgt[j];
    }

#pragma unroll
    for (int k = 0; k < 8; ++k) {
        float s = 0.f;
#pragma unroll
        for (int di = 0; di < 5; ++di)
#pragma unroll
            for (int dj = 0; dj < 5; ++dj)
                s = fmaf(wgt[di * 5 + dj], sl[k][ty + di][tx + dj], s);
        float sc = sl[k][ty + 2][tx + 2];
        float numk = s * sc;
        float denk = w1 * sc;
#pragma unroll
        for (int sft = 32; sft > 0; sft >>= 1) {
            numk += __shfl_xor(numk, sft, 64);
            denk += __shfl_xor(denk, sft, 64);
        }
        if (t == 0) {
            atomicAdd(&acc[n * 8 + k], numk);
            atomicAdd(&acc[32 + n * 8 + k], denk);
        }
    }
}

// ---------------- modularity on images (unchanged) ---------------------------
__global__ __launch_bounds__(256) void modularity128_k(
    const float* __restrict__ it, const float* __restrict__ seg,
    float* __restrict__ acc)
{
    const float inv2s2 = 1.0f / (2.0f * 0.2f * 0.2f);
    int tid = blockIdx.x * 256 + threadIdx.x;
    int lane = threadIdx.x & 63;
    int w = tid & 127;
    int h = (tid >> 7) & 127;
    int n = tid >> 14;

    const float* cp = it + (size_t)tid * 3;
    float c0 = cp[0], c1 = cp[1], c2 = cp[2];
    float segc[8], num[8];
#pragma unroll
    for (int k = 0; k < 8; ++k) {
        segc[k] = seg[((size_t)(n * 8 + k) * 128 + h) * 128 + w];
        num[k] = 0.f;
    }
    float w1 = 0.f;

    for (int di = -2; di <= 2; ++di) {
        int h2 = h + di;
        if (h2 < 0 || h2 >= 128) continue;
        for (int dj = -2; dj <= 2; ++dj) {
            int w2 = w + dj;
            if (w2 < 0 || w2 >= 128) continue;
            const float* vp = it + ((size_t)((n * 128 + h2) * 128 + w2)) * 3;
            float d0 = c0 - vp[0], d1 = c1 - vp[1], d2v = c2 - vp[2];
            float d2 = fmaf(d2v, d2v, fmaf(d1, d1, d0 * d0));
            float wgt = expf(-d2 * inv2s2);
            w1 += wgt;
            const float* sp = seg + ((size_t)(n * 8) * 128 + h2) * 128 + w2;
#pragma unroll
            for (int k = 0; k < 8; ++k)
                num[k] = fmaf(sp[(size_t)k * 16384], wgt, num[k]);
        }
    }

    float val;
#pragma unroll
    for (int k = 0; k < 8; ++k) {
        val = num[k] * segc[k];
#pragma unroll
        for (int s = 32; s > 0; s >>= 1) val += __shfl_xor(val, s, 64);
        if (lane == 0) atomicAdd(&acc[64 + n * 8 + k], val);
        val = w1 * segc[k];
#pragma unroll
        for (int s = 32; s > 0; s >>= 1) val += __shfl_xor(val, s, 64);
        if (lane == 0) atomicAdd(&acc[96 + n * 8 + k], val);
    }
}

__global__ void finalize_k(const float* __restrict__ acc, float* __restrict__ out)
{
    int l = threadIdx.x;
    float v = 0.f;
    if (l < 32) v = acc[l] / acc[32 + l] + acc[64 + l] / acc[96 + l];
#pragma unroll
    for (int s = 32; s > 0; s >>= 1) v += __shfl_xor(v, s, 64);
    if (l == 0) out[0] = v * (1.0f / 64.0f);
}

extern "C" void kernel_launch(void* const* d_in, const int* in_sizes, int n_in,
                              void* d_out, int out_size, void* d_ws, size_t ws_size,
                              hipStream_t stream)
{
    const float* images = (const float*)d_in[0];
    const float* seg    = (const float*)d_in[1];
    const float* w1 = (const float*)d_in[2]; const float* b1 = (const float*)d_in[3];
    const float* w2 = (const float*)d_in[4]; const float* b2 = (const float*)d_in[5];
    const float* w3 = (const float*)d_in[6]; const float* b3 = (const float*)d_in[7];
    const float* w4 = (const float*)d_in[8]; const float* b4 = (const float*)d_in[9];
    float* out = (float*)d_out;
    char* ws = (char*)d_ws;
    short* C2   = (short*)(ws + OFF_C2);
    short* PAD2 = (short*)(ws + OFF_PAD2);
    short* PAD3 = (short*)(ws + OFF_PAD3);
    short* PAD4 = (short*)(ws + OFF_PAD4);
    float* FICH = (float*)(ws + OFF_FICH);
    short* WP2  = (short*)(ws + OFF_WP2);
    short* WP3  = (short*)(ws + OFF_WP3);
    short* WP4  = (short*)(ws + OFF_WP4);
    float* DS   = (float*)(ws + OFF_DS);
    float* IT   = (float*)(ws + OFF_IT);
    float* ST   = (float*)(ws + OFF_ST);
    float* AC   = (float*)(ws + OFF_AC);

    // zero halos + accumulators
    hipMemsetAsync(PAD2, 0, PAD2_BYTES, stream);
    hipMemsetAsync(PAD3, 0, PAD3_BYTES, stream);
    hipMemsetAsync(PAD4, 0, PAD4_BYTES, stream);
    zero_k<<<1, 512, 0, stream>>>(AC);

    // weight prepack (bf16 fragment order)
    prepack_w<<<144, 256, 0, stream>>>(w2, WP2, 64, 4, 36864);
    prepack_w<<<288, 256, 0, stream>>>(w3, WP3, 64, 8, 73728);
    prepack_w<<<576, 256, 0, stream>>>(w4, WP4, 128, 8, 147456);

    // VGG stem
    conv1_bf16<<<2048, 256, 0, stream>>>(images, w1, b1, PAD2);
    conv_mfma<64, 64, 128, 128, 0><<<2048, 256, 0, stream>>>(PAD2, WP2, b2, C2);
    maxpool_nhwc<<<512, 256, 0, stream>>>((const ushortT*)C2, (ushortT*)PAD3);
    conv_mfma<64, 128, 64, 64, 1><<<1024, 256, 0, stream>>>(PAD3, WP3, b3, PAD4);
    conv_mfma<128, 128, 64, 64, 2><<<1024, 256, 0, stream>>>(PAD4, WP4, b4, FICH);

    // BN (scale-only; mean cancels in d2)
    bnsum_nhwc<<<256, 256, 0, stream>>>(FICH, AC + 128);
    stats_fin<<<1, 128, 0, stream>>>(AC + 128, ST);
    scale_fich<<<2048, 256, 0, stream>>>(FICH, ST);

    // image branch
    bn_stats_k<<<3, 256, 0, stream>>>(images, ST + 256, 3, 16384, 4);
    norm_transpose_i_k<<<256, 256, 0, stream>>>(images, ST + 256, IT);
    avgpool2_k<<<512, 256, 0, stream>>>(seg, DS, 131072);

    // modularity terms
    modularity64_v2<<<256, 64, 0, stream>>>(FICH, DS, AC);
    modularity128_k<<<256, 256, 0, stream>>>(IT, seg, AC);

    finalize_k<<<1, 64, 0, stream>>>(AC, out);
}